// Round 7
// baseline (372.947 us; speedup 1.0000x reference)
//
#include <hip/hip_runtime.h>

typedef __attribute__((ext_vector_type(8))) short short8;
typedef __attribute__((ext_vector_type(4))) float f32x4;
typedef unsigned int u32;

#define CIN   128
#define COUT  256
#define H     112
#define W     112
#define OH    110
#define OW    110
#define KHW   9
#define TH    8
#define TW    32
#define IHH   10              // TH+2
#define IWW   34              // TW+2
#define NPIX  340             // IHH*IWW
#define XB    (NPIX*8*16)     // 43520 B: x half-tile, 2720 16B slots
#define WB    16384           // w tap-half: 128 cout * 8 slots * 16B

__device__ __forceinline__ short f2b(float f) {
  unsigned u = __builtin_bit_cast(unsigned, f);
  unsigned r = (u + 0x7FFFu + ((u >> 16) & 1u)) >> 16;  // RNE
  return (short)r;
}

__device__ __forceinline__ void gload16(const void* g, void* l) {
  __builtin_amdgcn_global_load_lds(
      (const __attribute__((address_space(1))) u32*)g,
      (__attribute__((address_space(3))) u32*)l, 16, 0, 0);
}

// XT path LDS layouts:
//   x: [G(0..7)][p(0..339)] 16B slots (linear, forced by global_load_lds) —
//      B-reads are 16 contiguous slots => conflict-free, NO swizzle needed.
//   w: [c(128)][G(8)] 16B slots, source-XOR swizzle gsw = G^(c&7) applied on
//      the per-lane global source and on the read => bijective => correct.
// global_load_lds contract: LDS dest = readfirstlane(base) + lane*16. All
// DMA issues are UNCONDITIONAL across the wave (OOB lanes redirect their
// per-lane GLOBAL source to a zero page) — only prefix tail-masking allowed.

template<bool XT, bool WT>
__global__ __launch_bounds__(512, 4)
void conv_main(const float* __restrict__ x, const float* __restrict__ wgt,
               const short* __restrict__ wt, const short* __restrict__ xt,
               const short* __restrict__ zp, float* __restrict__ out) {
  __shared__ __align__(16) char smem[XB + 2*WB];   // 76288 B -> 2 blocks/CU
  char* sx = smem;
  char* sw = smem + XB;

  const int tid = threadIdx.x;

  // XCD-chunked bijective swizzle (3584 % 8 == 0)
  const int nb  = gridDim.x;
  const int swz = (blockIdx.x & 7) * (nb >> 3) + (blockIdx.x >> 3);
  const int b    = swz / 112;            // 2 cblk * 4 tw * 14 th
  const int rem  = swz - b * 112;
  const int cblk = rem / 56;
  const int rem2 = rem - cblk * 56;
  const int t_w  = rem2 / 14;
  const int t_h  = rem2 - t_w * 14;
  const int h0 = t_h * TH, w0 = t_w * TW;

  auto stage_x = [&](int hh) {
    if (XT) {
      const short* xtb = xt + (size_t)b * (H*W*CIN);
      #pragma unroll
      for (int it = 0; it < 6; ++it) {
        int u = it*512 + tid;            // [G][p] slot index, 2720 total
        if (u < 8*NPIX) {                // prefix-masked tail only: safe
          int G = u / NPIX, p = u - G*NPIX;
          int iy = p / IWW, ix = p - iy * IWW;
          int gy = h0 + iy, gx = w0 + ix;
          const short* src = (gy < H && gx < W)
              ? xtb + ((size_t)gy*W + gx)*CIN + hh*64 + G*8
              : zp;                      // OOB -> zero page (per-lane src ok)
          gload16(src, sx + u*16);
        }
      }
    } else {
      const float* xh = x + (size_t)b * CIN * (H*W) + (size_t)(hh*64) * (H*W);
      for (int u = tid; u < 8 * NPIX; u += 512) {
        int G = u / NPIX, p = u - G * NPIX;
        int iy = p / IWW, ix = p - iy * IWW;
        int gy = h0 + iy, gx = w0 + ix;
        short8 v = {0,0,0,0,0,0,0,0};
        if (gy < H && gx < W) {
          const float* s = xh + (size_t)(G*8) * (H*W) + gy * W + gx;
          #pragma unroll
          for (int j = 0; j < 8; ++j) v[j] = f2b(s[j * (H*W)]);
        }
        *(short8*)(sx + p*128 + ((G ^ (p & 7)) << 4)) = v;
      }
    }
  };

  auto bx_addr = [&](int g, int p) -> const char* {
    if (XT) return sx + (g*NPIX + p) * 16;
    else    return sx + p*128 + ((g ^ (p & 7)) << 4);
  };

  auto stage_w = [&](int st, int buf) {
    int hh = st / 9, tap = st - hh * 9;
    if (WT) {
      const short* base = wt + (size_t)tap * (COUT*CIN)
                             + (size_t)(cblk*128) * CIN + hh * 64;
      #pragma unroll
      for (int it = 0; it < 2; ++it) {
        int slot = it * 512 + tid;            // 1024 slots of 16B
        int c = slot >> 3, gsw = (slot & 7) ^ (c & 7);
        gload16(base + c * CIN + gsw * 8, sw + buf*WB + slot * 16);
      }
    } else {
      #pragma unroll
      for (int it = 0; it < 2; ++it) {
        int slot = it * 512 + tid;
        int c = slot >> 3, gsw = (slot & 7) ^ (c & 7);
        int cout = cblk*128 + c;
        short8 v;
        #pragma unroll
        for (int j = 0; j < 8; ++j) {
          int cin = hh*64 + gsw*8 + j;
          v[j] = f2b(wgt[cout*(CIN*KHW) + cin*KHW + tap]);
        }
        *(short8*)(sw + buf*WB + slot * 16) = v;
      }
    }
  };

  const int lane = tid & 63;
  const int wid  = tid >> 6;
  const int wm = wid >> 2;        // 0..1 -> couts [wm*64, +64) of block's 128
  const int wn = wid & 3;         // 0..3 -> rows {2wn, 2wn+1}
  const int l15 = lane & 15;
  const int kgrp = lane >> 4;     // 0..3

  f32x4 acc[4][4] = {};

  stage_x(0);
  stage_w(0, 0);
  __syncthreads();

  for (int st = 0; st < 18; ++st) {          // 2 cin-halves x 9 taps
    if (st + 1 < 18) stage_w(st + 1, (st + 1) & 1);

    const int tap = st % 9;
    const int kh = tap / 3, kw = tap - (tap/3)*3;
    const char* swb = sw + (st & 1) * WB;

    #pragma unroll
    for (int s = 0; s < 2; ++s) {            // two K=32 steps over 64 cins
      const int g = s*4 + kgrp;
      const int aslot = (g ^ (l15 & 7)) << 4;
      short8 a[4];
      #pragma unroll
      for (int mi = 0; mi < 4; ++mi)
        a[mi] = *(const short8*)(swb + (wm*64 + mi*16 + l15) * 128 + aslot);
      short8 bf[4];
      #pragma unroll
      for (int ni = 0; ni < 4; ++ni) {
        int p = (2*wn + (ni >> 1) + kh) * IWW + (ni & 1)*16 + l15 + kw;
        bf[ni] = *(const short8*)bx_addr(g, p);
      }
      #pragma unroll
      for (int mi = 0; mi < 4; ++mi)
        #pragma unroll
        for (int ni = 0; ni < 4; ++ni)
          acc[mi][ni] = __builtin_amdgcn_mfma_f32_16x16x32_bf16(a[mi], bf[ni], acc[mi][ni], 0, 0, 0);
    }

    if (st == 8) {
      __syncthreads();      // x half-0 readers done; w(9) DMA drained here
      stage_x(1);
      __syncthreads();      // drains x half-1 DMA
    } else {
      __syncthreads();
    }
  }

  // ---- epilogue: C layout col=l15 (px), row=4*kgrp+r (cout) [m89] ----
  float* ob = out + (size_t)b * COUT * (OH*OW);
  #pragma unroll
  for (int ni = 0; ni < 4; ++ni) {
    int oh = h0 + 2*wn + (ni >> 1);
    int ow = w0 + (ni & 1)*16 + l15;
    if (oh < OH && ow < OW) {
      #pragma unroll
      for (int mi = 0; mi < 4; ++mi) {
        #pragma unroll
        for (int r = 0; r < 4; ++r) {
          int cout = cblk*128 + wm*64 + mi*16 + kgrp*4 + r;
          ob[(size_t)cout*(OH*OW) + oh*OW + ow] = acc[mi][ni][r];
        }
      }
    }
  }
}

// one-time weight transpose+cvt: wt[tap][cout][cin] bf16; also zeros the
// 256-B zero page that follows wt in the workspace.
__global__ void wprep(const float* __restrict__ wgt, short* __restrict__ wt,
                      short* __restrict__ zp) {
  int idx = blockIdx.x * 256 + threadIdx.x;
  if (idx < 128) zp[idx] = 0;
  if (idx >= KHW*COUT*CIN) return;
  int khw  = idx / (COUT*CIN);
  int rem  = idx - khw*(COUT*CIN);
  int cout = rem >> 7, cin = rem & 127;
  wt[idx] = f2b(wgt[cout*(CIN*KHW) + cin*KHW + khw]);
}

// one-time x transpose+cvt: xt[b][h][w][cin] bf16, via padded LDS tile.
__global__ __launch_bounds__(256)
void xprep(const float* __restrict__ x, short* __restrict__ xt) {
  __shared__ short lsh[CIN * 113];   // 28928 B
  const int bh = blockIdx.x;
  const int b = bh / H, h = bh - b * H;
  const float* src = x + ((size_t)b * CIN * H + h) * W;
  for (int u = threadIdx.x; u < CIN * W; u += 256) {
    int c = u / W, w = u - c * W;
    lsh[c * 113 + w] = f2b(src[(size_t)c * (H*W) + w]);
  }
  __syncthreads();
  short* dst = xt + (size_t)bh * (W * CIN);
  for (int o = threadIdx.x; o < W * CIN / 8; o += 256) {   // 1792
    int w = o >> 4, s = o & 15;
    short8 v;
    #pragma unroll
    for (int j = 0; j < 8; ++j) v[j] = lsh[(s*8 + j) * 113 + w];
    *(short8*)(dst + o * 8) = v;
  }
}

extern "C" void kernel_launch(void* const* d_in, const int* in_sizes, int n_in,
                              void* d_out, int out_size, void* d_ws, size_t ws_size,
                              hipStream_t stream) {
  const float* x   = (const float*)d_in[0];
  const float* wgt = (const float*)d_in[1];
  float* out = (float*)d_out;
  const size_t wt_bytes = (size_t)(KHW*COUT*CIN) * sizeof(short);   // 589824
  const size_t zp_bytes = 256;
  const size_t xt_bytes = (size_t)32 * H * W * CIN * sizeof(short); // 102.76 MB
  dim3 grid(3584);   // 2 cblk x 4 tw x 14 th x 32 b
  if (ws_size >= wt_bytes + zp_bytes + xt_bytes) {
    short* wt = (short*)d_ws;
    short* zp = (short*)((char*)d_ws + wt_bytes);
    short* xt = (short*)((char*)d_ws + wt_bytes + zp_bytes);
    wprep<<<(KHW*COUT*CIN + 255)/256, 256, 0, stream>>>(wgt, wt, zp);
    xprep<<<32 * H, 256, 0, stream>>>(x, xt);
    conv_main<true, true><<<grid, 512, 0, stream>>>(x, wgt, wt, xt, zp, out);
  } else if (ws_size >= wt_bytes + zp_bytes) {
    short* wt = (short*)d_ws;
    short* zp = (short*)((char*)d_ws + wt_bytes);
    wprep<<<(KHW*COUT*CIN + 255)/256, 256, 0, stream>>>(wgt, wt, zp);
    conv_main<false, true><<<grid, 512, 0, stream>>>(x, wgt, wt, nullptr, zp, out);
  } else {
    conv_main<false, false><<<grid, 512, 0, stream>>>(x, wgt, nullptr, nullptr, nullptr, out);
  }
}

// Round 8
// 356.446 us; speedup vs baseline: 1.0463x; 1.0463x over previous
//
#include <hip/hip_runtime.h>

typedef __attribute__((ext_vector_type(8))) short short8;
typedef __attribute__((ext_vector_type(4))) float f32x4;
typedef unsigned int u32;

#define CIN   128
#define COUT  256
#define H     112
#define W     112
#define OH    110
#define OW    110
#define KHW   9
#define TH    8
#define TW    32
#define IHH   10              // TH+2
#define IWW   34              // TW+2
#define NPIX  340             // IHH*IWW
#define XB    (NPIX*8*16)     // 43520 B: x half-tile, 2720 16B slots
#define WB    16384           // w tap-half: 128 cout * 8 slots * 16B

__device__ __forceinline__ short f2b(float f) {
  unsigned u = __builtin_bit_cast(unsigned, f);
  unsigned r = (u + 0x7FFFu + ((u >> 16) & 1u)) >> 16;  // RNE
  return (short)r;
}

__device__ __forceinline__ void gload16(const void* g, void* l) {
  __builtin_amdgcn_global_load_lds(
      (const __attribute__((address_space(1))) u32*)g,
      (__attribute__((address_space(3))) u32*)l, 16, 0, 0);
}

// x LDS layout (R5's measured-conflict-free one, now produced by DMA):
//   slot(p,G) = p*8 + (G ^ (p&7)); byte = p*128 + ((G^(p&7))<<4).
//   DMA writes linearly (lane u -> slot u); the swizzle is applied on the
//   PER-LANE GLOBAL SOURCE instead: lane u loads (p=u>>3, Geff=(u&7)^(p&7)).
//   Same involution on write-source and read => bijective => correct (m173).
// w LDS: [c(128)][G(8)] 16B slots, source-XOR gsw = G^(c&7), read with same.
// global_load_lds contract: LDS dest = readfirstlane(base) + lane*16. All
// DMA issues UNCONDITIONAL across the wave (OOB lanes redirect their global
// source to a zero page); only prefix tail-masking allowed.

template<bool XT, bool WT>
__global__ __launch_bounds__(512, 4)
void conv_main(const float* __restrict__ x, const float* __restrict__ wgt,
               const short* __restrict__ wt, const short* __restrict__ xt,
               const short* __restrict__ zp, float* __restrict__ out) {
  __shared__ __align__(16) char smem[XB + 2*WB];   // 76288 B -> 2 blocks/CU
  char* sx = smem;
  char* sw = smem + XB;

  const int tid = threadIdx.x;

  // XCD-chunked bijective swizzle (3584 % 8 == 0)
  const int nb  = gridDim.x;
  const int swz = (blockIdx.x & 7) * (nb >> 3) + (blockIdx.x >> 3);
  const int b    = swz / 112;            // 2 cblk * 4 tw * 14 th
  const int rem  = swz - b * 112;
  const int cblk = rem / 56;
  const int rem2 = rem - cblk * 56;
  const int t_w  = rem2 / 14;
  const int t_h  = rem2 - t_w * 14;
  const int h0 = t_h * TH, w0 = t_w * TW;

  auto stage_x = [&](int hh) {
    if (XT) {
      const short* xtb = xt + (size_t)b * (H*W*CIN);
      #pragma unroll
      for (int it = 0; it < 6; ++it) {
        int u = it*512 + tid;            // slot index, 2720 total
        if (u < 8*NPIX) {                // prefix-masked tail only: safe
          int p = u >> 3;                // pixel 0..339
          int Geff = (u & 7) ^ (p & 7);  // pre-swizzled source fragment
          int iy = p / IWW, ix = p - iy * IWW;
          int gy = h0 + iy, gx = w0 + ix;
          const short* src = (gy < H && gx < W)
              ? xtb + ((size_t)gy*W + gx)*CIN + hh*64 + Geff*8
              : zp;                      // OOB -> zero page (per-lane src ok)
          gload16(src, sx + u*16);
        }
      }
    } else {
      const float* xh = x + (size_t)b * CIN * (H*W) + (size_t)(hh*64) * (H*W);
      for (int u = tid; u < 8 * NPIX; u += 512) {
        int G = u / NPIX, p = u - G * NPIX;
        int iy = p / IWW, ix = p - iy * IWW;
        int gy = h0 + iy, gx = w0 + ix;
        short8 v = {0,0,0,0,0,0,0,0};
        if (gy < H && gx < W) {
          const float* s = xh + (size_t)(G*8) * (H*W) + gy * W + gx;
          #pragma unroll
          for (int j = 0; j < 8; ++j) v[j] = f2b(s[j * (H*W)]);
        }
        *(short8*)(sx + p*128 + ((G ^ (p & 7)) << 4)) = v;
      }
    }
  };

  auto stage_w = [&](int st, int buf) {
    int hh = st / 9, tap = st - hh * 9;
    if (WT) {
      const short* base = wt + (size_t)tap * (COUT*CIN)
                             + (size_t)(cblk*128) * CIN + hh * 64;
      #pragma unroll
      for (int it = 0; it < 2; ++it) {
        int slot = it * 512 + tid;            // 1024 slots of 16B
        int c = slot >> 3, gsw = (slot & 7) ^ (c & 7);
        gload16(base + c * CIN + gsw * 8, sw + buf*WB + slot * 16);
      }
    } else {
      #pragma unroll
      for (int it = 0; it < 2; ++it) {
        int slot = it * 512 + tid;
        int c = slot >> 3, gsw = (slot & 7) ^ (c & 7);
        int cout = cblk*128 + c;
        short8 v;
        #pragma unroll
        for (int j = 0; j < 8; ++j) {
          int cin = hh*64 + gsw*8 + j;
          v[j] = f2b(wgt[cout*(CIN*KHW) + cin*KHW + tap]);
        }
        *(short8*)(sw + buf*WB + slot * 16) = v;
      }
    }
  };

  const int lane = tid & 63;
  const int wid  = tid >> 6;
  const int wm = wid >> 2;        // 0..1 -> couts [wm*64, +64) of block's 128
  const int wn = wid & 3;         // 0..3 -> rows {2wn, 2wn+1}
  const int l15 = lane & 15;
  const int kgrp = lane >> 4;     // 0..3

  f32x4 acc[4][4] = {};

  stage_x(0);
  stage_w(0, 0);
  __syncthreads();

  for (int st = 0; st < 18; ++st) {          // 2 cin-halves x 9 taps
    if (st + 1 < 18) stage_w(st + 1, (st + 1) & 1);

    const int tap = st % 9;
    const int kh = tap / 3, kw = tap - (tap/3)*3;
    const char* swb = sw + (st & 1) * WB;

    #pragma unroll
    for (int s = 0; s < 2; ++s) {            // two K=32 steps over 64 cins
      const int g = s*4 + kgrp;
      const int aslot = (g ^ (l15 & 7)) << 4;
      short8 a[4];
      #pragma unroll
      for (int mi = 0; mi < 4; ++mi)
        a[mi] = *(const short8*)(swb + (wm*64 + mi*16 + l15) * 128 + aslot);
      short8 bf[4];
      #pragma unroll
      for (int ni = 0; ni < 4; ++ni) {
        int p = (2*wn + (ni >> 1) + kh) * IWW + (ni & 1)*16 + l15 + kw;
        bf[ni] = *(const short8*)(sx + p*128 + ((g ^ (p & 7)) << 4));
      }
      #pragma unroll
      for (int mi = 0; mi < 4; ++mi)
        #pragma unroll
        for (int ni = 0; ni < 4; ++ni)
          acc[mi][ni] = __builtin_amdgcn_mfma_f32_16x16x32_bf16(a[mi], bf[ni], acc[mi][ni], 0, 0, 0);
    }

    if (st == 8) {
      __syncthreads();      // x half-0 readers done; w(9) DMA drained here
      stage_x(1);
      __syncthreads();      // drains x half-1 DMA
    } else {
      __syncthreads();
    }
  }

  // ---- epilogue: C layout col=l15 (px), row=4*kgrp+r (cout) [m89] ----
  float* ob = out + (size_t)b * COUT * (OH*OW);
  #pragma unroll
  for (int ni = 0; ni < 4; ++ni) {
    int oh = h0 + 2*wn + (ni >> 1);
    int ow = w0 + (ni & 1)*16 + l15;
    if (oh < OH && ow < OW) {
      #pragma unroll
      for (int mi = 0; mi < 4; ++mi) {
        #pragma unroll
        for (int r = 0; r < 4; ++r) {
          int cout = cblk*128 + wm*64 + mi*16 + kgrp*4 + r;
          ob[(size_t)cout*(OH*OW) + oh*OW + ow] = acc[mi][ni][r];
        }
      }
    }
  }
}

// one-time weight transpose+cvt: wt[tap][cout][cin] bf16; also zeros the
// 256-B zero page that follows wt in the workspace.
__global__ void wprep(const float* __restrict__ wgt, short* __restrict__ wt,
                      short* __restrict__ zp) {
  int idx = blockIdx.x * 256 + threadIdx.x;
  if (idx < 128) zp[idx] = 0;
  if (idx >= KHW*COUT*CIN) return;
  int khw  = idx / (COUT*CIN);
  int rem  = idx - khw*(COUT*CIN);
  int cout = rem >> 7, cin = rem & 127;
  wt[idx] = f2b(wgt[cout*(CIN*KHW) + cin*KHW + khw]);
}

// one-time x transpose+cvt: xt[b][h][w][cin] bf16, via padded LDS tile.
__global__ __launch_bounds__(256)
void xprep(const float* __restrict__ x, short* __restrict__ xt) {
  __shared__ short lsh[CIN * 113];   // 28928 B
  const int bh = blockIdx.x;
  const int b = bh / H, h = bh - b * H;
  const float* src = x + ((size_t)b * CIN * H + h) * W;
  for (int u = threadIdx.x; u < CIN * W; u += 256) {
    int c = u / W, w = u - c * W;
    lsh[c * 113 + w] = f2b(src[(size_t)c * (H*W) + w]);
  }
  __syncthreads();
  short* dst = xt + (size_t)bh * (W * CIN);
  for (int o = threadIdx.x; o < W * CIN / 8; o += 256) {   // 1792
    int w = o >> 4, s = o & 15;
    short8 v;
    #pragma unroll
    for (int j = 0; j < 8; ++j) v[j] = lsh[(s*8 + j) * 113 + w];
    *(short8*)(dst + o * 8) = v;
  }
}

extern "C" void kernel_launch(void* const* d_in, const int* in_sizes, int n_in,
                              void* d_out, int out_size, void* d_ws, size_t ws_size,
                              hipStream_t stream) {
  const float* x   = (const float*)d_in[0];
  const float* wgt = (const float*)d_in[1];
  float* out = (float*)d_out;
  const size_t wt_bytes = (size_t)(KHW*COUT*CIN) * sizeof(short);   // 589824
  const size_t zp_bytes = 256;
  const size_t xt_bytes = (size_t)32 * H * W * CIN * sizeof(short); // 102.76 MB
  dim3 grid(3584);   // 2 cblk x 4 tw x 14 th x 32 b
  if (ws_size >= wt_bytes + zp_bytes + xt_bytes) {
    short* wt = (short*)d_ws;
    short* zp = (short*)((char*)d_ws + wt_bytes);
    short* xt = (short*)((char*)d_ws + wt_bytes + zp_bytes);
    wprep<<<(KHW*COUT*CIN + 255)/256, 256, 0, stream>>>(wgt, wt, zp);
    xprep<<<32 * H, 256, 0, stream>>>(x, xt);
    conv_main<true, true><<<grid, 512, 0, stream>>>(x, wgt, wt, xt, zp, out);
  } else if (ws_size >= wt_bytes + zp_bytes) {
    short* wt = (short*)d_ws;
    short* zp = (short*)((char*)d_ws + wt_bytes);
    wprep<<<(KHW*COUT*CIN + 255)/256, 256, 0, stream>>>(wgt, wt, zp);
    conv_main<false, true><<<grid, 512, 0, stream>>>(x, wgt, wt, nullptr, zp, out);
  } else {
    conv_main<false, false><<<grid, 512, 0, stream>>>(x, wgt, nullptr, nullptr, nullptr, out);
  }
}